// Round 1
// baseline (727.143 us; speedup 1.0000x reference)
//
#include <hip/hip_runtime.h>
#include <hip/hip_bf16.h>
#include <stdint.h>
#include <string.h>

using bf16 = __hip_bfloat16;
typedef __attribute__((ext_vector_type(8))) short bf16x8;   // 8 bf16 (4 VGPRs) MFMA A/B frag
typedef __attribute__((ext_vector_type(4))) float f32x4;    // MFMA C/D frag

#define DEV static __device__ __forceinline__

DEV bf16 tobf(float f) { return __float2bfloat16(f); }
DEV float tof(bf16 h) { return __bfloat162float(h); }
DEV unsigned short bfraw(bf16 h) { unsigned short u; __builtin_memcpy(&u, &h, 2); return u; }

// async global->LDS, 16B per lane. LDS dest semantics: wave-uniform base + lane*16.
DEV void gload_lds16(const void* g, void* l) {
  __builtin_amdgcn_global_load_lds((__attribute__((address_space(1))) void*)g,
                                   (__attribute__((address_space(3))) void*)l,
                                   16, 0, 0);
}

// ---------------- prep kernels ----------------

// dst[n][k] = (bf16)src[k][n]; src is K x N row-major. block (32,8), grid (K/32, N/32)
__global__ void transpose_cast_k(const float* __restrict__ src, bf16* __restrict__ dst,
                                 int K, int N) {
  __shared__ float tile[32][33];
  int kb = blockIdx.x * 32, nb = blockIdx.y * 32;
  int tx = threadIdx.x, ty = threadIdx.y;
#pragma unroll
  for (int i = 0; i < 32; i += 8)
    tile[ty + i][tx] = src[(size_t)(kb + ty + i) * N + nb + tx];
  __syncthreads();
#pragma unroll
  for (int i = 0; i < 32; i += 8)
    dst[(size_t)(nb + ty + i) * K + kb + tx] = tobf(tile[tx][ty + i]);
}

__global__ void cast_x_k(const float* __restrict__ src, bf16* __restrict__ dst) {
  int i = blockIdx.x * blockDim.x + threadIdx.x;  // one float4 per thread
  float4 v = ((const float4*)src)[i];
  bf16 t[4] = {tobf(v.x), tobf(v.y), tobf(v.z), tobf(v.w)};
  uint2 p; __builtin_memcpy(&p, t, 8);
  ((uint2*)dst)[i] = p;
}

// cos/sin tables: [S][64]. grid S blocks x 64 threads.
__global__ void rope_table_k(const int* __restrict__ pos, float* __restrict__ cosT,
                             float* __restrict__ sinT) {
  int s = blockIdx.x, i = threadIdx.x;
  double inv = exp(-((double)(2 * i) / 128.0) * log(10000.0));
  float f = (float)pos[s] * (float)inv;
  cosT[s * 64 + i] = cosf(f);
  sinT[s * 64 + i] = sinf(f);
}

// g1,g2 = sigmoid(X @ Wg + bg), fp32. One block per token.
__global__ __launch_bounds__(256) void gates_k(
    const float* __restrict__ X, const float* __restrict__ Wg1, const float* __restrict__ bg1,
    const float* __restrict__ Wg2, const float* __restrict__ bg2,
    float* __restrict__ g1, float* __restrict__ g2) {
  __shared__ float xs[2048];
  int t = blockIdx.x;
  const float* xr = X + (size_t)t * 2048;
  for (int i = threadIdx.x; i < 2048; i += 256) xs[i] = xr[i];
  __syncthreads();
  int o = threadIdx.x >> 3, j = threadIdx.x & 7;  // 32 outputs x 8 threads
  int h = o & 15;
  const float* W = (o < 16) ? Wg1 : Wg2;
  float s = 0.f;
  for (int k = j; k < 2048; k += 8) s += xs[k] * W[(size_t)k * 16 + h];
  s += __shfl_down(s, 4); s += __shfl_down(s, 2); s += __shfl_down(s, 1);
  if (j == 0) {
    float b = (o < 16) ? bg1[h] : bg2[h];
    float v = 1.f / (1.f + __expf(-(s + b)));
    (o < 16 ? g1 : g2)[(size_t)t * 16 + h] = v;
  }
}

// RoPE in place on qkv: q cols [0,2048), k cols [2048,2560). One thread per (token, head, pair).
__global__ void rope_apply_k(bf16* __restrict__ qkv, const float* __restrict__ cosT,
                             const float* __restrict__ sinT) {
  int idx = blockIdx.x * 256 + threadIdx.x;  // 4096 * 1280 total
  int t = idx / 1280, r = idx % 1280;
  int head = r >> 6, i = r & 63;
  int s = t & 2047;
  size_t base = (size_t)t * 3072 + (head < 16 ? head * 128 : 2048 + (head - 16) * 128);
  float c = cosT[s * 64 + i], sn = sinT[s * 64 + i];
  float x0 = tof(qkv[base + i]), x1 = tof(qkv[base + i + 64]);
  qkv[base + i]      = tobf(x0 * c - x1 * sn);
  qkv[base + i + 64] = tobf(x1 * c + x0 * sn);
}

// ---------------- GEMM: C = A(MxK) * Bt(NxK)^T ----------------
// m97 structure: 128x128 tile, BK=32, 4 waves (2x2, 64x64 each), global_load_lds x16B.
template <bool OUT_BF16>
__global__ __launch_bounds__(256, 2) void gemm_bt_k(
    const bf16* __restrict__ A, const bf16* __restrict__ Bt, void* __restrict__ Cout,
    int M, int N, int K) {
  constexpr int BK = 32;
  __shared__ bf16 sA[2][128 * BK];
  __shared__ bf16 sB[2][128 * BK];
  const int tid = threadIdx.x, wave = tid >> 6, lane = tid & 63;
  const int lhi = lane >> 4, llo = lane & 15;
  const int wm = wave >> 1, wn = wave & 1;
  const int bm = blockIdx.y, bn = blockIdx.x;
  const bf16* Ag = A + (size_t)bm * 128 * K;
  const bf16* Bg = Bt + (size_t)bn * 128 * K;

  f32x4 acc[4][4];
#pragma unroll
  for (int m = 0; m < 4; m++)
#pragma unroll
    for (int n = 0; n < 4; n++) acc[m][n] = f32x4{0.f, 0.f, 0.f, 0.f};

  auto stage = [&](int buf, int kt) {
#pragma unroll
    for (int i = 0; i < 2; i++) {
      int c = i * 256 + tid, row = c >> 2, c8 = c & 3;
      gload_lds16(Ag + (size_t)row * K + kt * BK + c8 * 8, &sA[buf][c * 8]);
    }
#pragma unroll
    for (int i = 0; i < 2; i++) {
      int c = i * 256 + tid, row = c >> 2, c8 = c & 3;
      gload_lds16(Bg + (size_t)row * K + kt * BK + c8 * 8, &sB[buf][c * 8]);
    }
  };

  const int NT = K / BK;
  stage(0, 0);
  for (int kt = 0; kt < NT; kt++) {
    __syncthreads();  // drains this wave's global_load_lds (compiler emits vmcnt(0)) + syncs
    if (kt + 1 < NT) stage((kt + 1) & 1, kt + 1);
    const bf16* a_ = sA[kt & 1];
    const bf16* b_ = sB[kt & 1];
    bf16x8 af[4], bfr[4];
#pragma unroll
    for (int m = 0; m < 4; m++)
      af[m] = *(const bf16x8*)&a_[(wm * 64 + m * 16 + llo) * BK + lhi * 8];
#pragma unroll
    for (int n = 0; n < 4; n++)
      bfr[n] = *(const bf16x8*)&b_[(wn * 64 + n * 16 + llo) * BK + lhi * 8];
#pragma unroll
    for (int m = 0; m < 4; m++)
#pragma unroll
      for (int n = 0; n < 4; n++)
        acc[m][n] = __builtin_amdgcn_mfma_f32_16x16x32_bf16(af[m], bfr[n], acc[m][n], 0, 0, 0);
  }

  const int r0 = bm * 128 + wm * 64, c0 = bn * 128 + wn * 64;
  if (OUT_BF16) {
    bf16* C = (bf16*)Cout;
#pragma unroll
    for (int m = 0; m < 4; m++)
#pragma unroll
      for (int n = 0; n < 4; n++)
#pragma unroll
        for (int r = 0; r < 4; r++)
          C[(size_t)(r0 + m * 16 + lhi * 4 + r) * N + (c0 + n * 16 + llo)] = tobf(acc[m][n][r]);
  } else {
    float* C = (float*)Cout;
#pragma unroll
    for (int m = 0; m < 4; m++)
#pragma unroll
      for (int n = 0; n < 4; n++)
#pragma unroll
        for (int r = 0; r < 4; r++)
          C[(size_t)(r0 + m * 16 + lhi * 4 + r) * N + (c0 + n * 16 + llo)] = acc[m][n][r];
  }
}

// ---------------- fused causal GQA attention + LN + gating ----------------
// grid (S/64, B*16). 4 waves/block; wave w owns q rows [qt*64+w*16, +16).
// KV tile = 64 rows staged in LDS; K as [64][128] and V^T as [128][64], both with
// (row&7)<<4 byte XOR swizzle (guide §6 G4) to kill 16-way bank conflicts on ds_read_b128.
__global__ __launch_bounds__(256, 2) void attn_k(
    const bf16* __restrict__ qkv, const float* __restrict__ g1, const float* __restrict__ g2,
    const float* __restrict__ lng, const float* __restrict__ lnb, bf16* __restrict__ aout) {
  constexpr int S = 2048, LD = 3072, NH = 16;
  const int qt = blockIdx.x, bh = blockIdx.y;
  const int b = bh >> 4, h = bh & 15, kvh = h >> 2;
  const int tid = threadIdx.x, wave = tid >> 6, lane = tid & 63;
  const int lhi = lane >> 4, llo = lane & 15;
  const size_t tok0 = (size_t)b * S;

  __shared__ bf16 sK[64 * 128];   // [kv][d], swizzled
  __shared__ bf16 sV[128 * 64];   // [d][kv] (transposed), swizzled
  __shared__ bf16 sP[4][16][72];  // per-wave P tile, padded

  const int qrow0 = qt * 64 + wave * 16;

  // Q fragments held in registers for the whole block row
  bf16x8 qf[4];
  {
    const bf16* qg = qkv + (tok0 + qrow0 + llo) * LD + h * 128;
#pragma unroll
    for (int dc = 0; dc < 4; dc++) qf[dc] = *(const bf16x8*)(qg + dc * 32 + lhi * 8);
  }

  f32x4 oacc[8];
#pragma unroll
  for (int i = 0; i < 8; i++) oacc[i] = f32x4{0.f, 0.f, 0.f, 0.f};
  float mrow[4] = {-1e30f, -1e30f, -1e30f, -1e30f};
  float lrow[4] = {0.f, 0.f, 0.f, 0.f};
  const float scale = 0.08838834764831845f;  // 1/sqrt(128)

  for (int kt = 0; kt <= qt; kt++) {
    __syncthreads();  // previous tile's reads complete before overwrite
    // ---- stage K tile [64][128], coalesced 16B, swizzled ----
#pragma unroll
    for (int i = 0; i < 4; i++) {
      int c = i * 256 + tid, row = c >> 4, c8 = c & 15;
      const bf16* kg = qkv + (tok0 + kt * 64 + row) * LD + 2048 + kvh * 128 + c8 * 8;
      int eidx = (row * 128 + c8 * 8) ^ ((row & 7) << 3);
      *(uint4*)&sK[eidx] = *(const uint4*)kg;
    }
    // ---- stage V^T tile [128][64] with g2 gating; kv-pair packed b32 writes,
    //      per-lane rotated j order -> conflict-free ----
#pragma unroll
    for (int i = 0; i < 2; i++) {
      int c = i * 256 + tid, kvp = c >> 4, c8 = c & 15;
      int kv0 = 2 * kvp;
      const bf16* v0 = qkv + (tok0 + kt * 64 + kv0) * LD + 2560 + kvh * 128 + c8 * 8;
      const bf16* v1 = v0 + LD;
      float gg0 = g2[(tok0 + kt * 64 + kv0) * NH + h];
      float gg1 = g2[(tok0 + kt * 64 + kv0 + 1) * NH + h];
      bf16x8 va = *(const bf16x8*)v0;
      bf16x8 vb = *(const bf16x8*)v1;
      uint32_t pk[8];
#pragma unroll
      for (int j = 0; j < 8; j++) {
        bf16 lo = tobf(tof(((const bf16*)&va)[j]) * gg0);
        bf16 hi = tobf(tof(((const bf16*)&vb)[j]) * gg1);
        pk[j] = (uint32_t)bfraw(lo) | ((uint32_t)bfraw(hi) << 16);
      }
#pragma unroll
      for (int j = 0; j < 8; j++) {
        int jj = (j + lane) & 7;
        int d = c8 * 8 + jj;
        int eidx = (d * 64 + kv0) ^ ((d & 7) << 3);
        *(uint32_t*)&sV[eidx] = pk[jj];
      }
    }
    __syncthreads();

    const bool diag = (kt == qt);
    // ---- QK^T: 4 col-tiles x 4 d-chunks ----
    f32x4 sc[4];
#pragma unroll
    for (int ct = 0; ct < 4; ct++) {
      f32x4 acc = f32x4{0.f, 0.f, 0.f, 0.f};
#pragma unroll
      for (int dc = 0; dc < 4; dc++) {
        int row = ct * 16 + llo;
        bf16x8 kf = *(const bf16x8*)&sK[(row * 128 + dc * 32 + lhi * 8) ^ ((row & 7) << 3)];
        acc = __builtin_amdgcn_mfma_f32_16x16x32_bf16(qf[dc], kf, acc, 0, 0, 0);
      }
      sc[ct] = acc;
    }
    // ---- scale + causal mask + online softmax ----
    float pm[4] = {-1e30f, -1e30f, -1e30f, -1e30f};
#pragma unroll
    for (int ct = 0; ct < 4; ct++) {
      int kv = kt * 64 + ct * 16 + llo;
#pragma unroll
      for (int r = 0; r < 4; r++) {
        float s = sc[ct][r] * scale;
        if (diag && kv > qrow0 + lhi * 4 + r) s = -1e30f;
        sc[ct][r] = s;
        pm[r] = fmaxf(pm[r], s);
      }
    }
#pragma unroll
    for (int r = 0; r < 4; r++) {
      float v = pm[r];
      v = fmaxf(v, __shfl_xor(v, 1));
      v = fmaxf(v, __shfl_xor(v, 2));
      v = fmaxf(v, __shfl_xor(v, 4));
      v = fmaxf(v, __shfl_xor(v, 8));
      float mnew = fmaxf(mrow[r], v);
      float al = __expf(mrow[r] - mnew);
      mrow[r] = mnew;
      lrow[r] *= al;
#pragma unroll
      for (int i = 0; i < 8; i++) oacc[i][r] *= al;
    }
    float rs[4] = {0.f, 0.f, 0.f, 0.f};
#pragma unroll
    for (int ct = 0; ct < 4; ct++) {
#pragma unroll
      for (int r = 0; r < 4; r++) {
        float p = __expf(sc[ct][r] - mrow[r]);
        rs[r] += p;
        sP[wave][lhi * 4 + r][ct * 16 + llo] = tobf(p);
      }
    }
#pragma unroll
    for (int r = 0; r < 4; r++) {
      float v = rs[r];
      v += __shfl_xor(v, 1); v += __shfl_xor(v, 2); v += __shfl_xor(v, 4); v += __shfl_xor(v, 8);
      lrow[r] += v;
    }
    // ---- PV: O += P * V_eff ----
#pragma unroll
    for (int kc = 0; kc < 2; kc++) {
      bf16x8 pf = *(const bf16x8*)&sP[wave][llo][kc * 32 + lhi * 8];
#pragma unroll
      for (int dt = 0; dt < 8; dt++) {
        int d = dt * 16 + llo;
        bf16x8 vf = *(const bf16x8*)&sV[(d * 64 + kc * 32 + lhi * 8) ^ ((d & 7) << 3)];
        oacc[dt] = __builtin_amdgcn_mfma_f32_16x16x32_bf16(pf, vf, oacc[dt], 0, 0, 0);
      }
    }
  }

  // ---- epilogue: 1/l, LayerNorm over head_dim, *g1, store bf16 ----
  float inv_l[4], mu[4], rstd[4];
  float ov[8][4];
  {
    float sum[4] = {0, 0, 0, 0}, sq[4] = {0, 0, 0, 0};
#pragma unroll
    for (int r = 0; r < 4; r++) inv_l[r] = 1.f / lrow[r];
#pragma unroll
    for (int dt = 0; dt < 8; dt++)
#pragma unroll
      for (int r = 0; r < 4; r++) {
        float v = oacc[dt][r] * inv_l[r];
        ov[dt][r] = v;
        sum[r] += v;
        sq[r] += v * v;
      }
#pragma unroll
    for (int r = 0; r < 4; r++) {
      float s1 = sum[r], s2 = sq[r];
      s1 += __shfl_xor(s1, 1); s1 += __shfl_xor(s1, 2); s1 += __shfl_xor(s1, 4); s1 += __shfl_xor(s1, 8);
      s2 += __shfl_xor(s2, 1); s2 += __shfl_xor(s2, 2); s2 += __shfl_xor(s2, 4); s2 += __shfl_xor(s2, 8);
      float m_ = s1 * (1.f / 128.f);
      float var = s2 * (1.f / 128.f) - m_ * m_;
      mu[r] = m_;
      rstd[r] = rsqrtf(var + 1e-5f);
    }
  }
#pragma unroll
  for (int r = 0; r < 4; r++) {
    int qr = qrow0 + lhi * 4 + r;
    float gg = g1[(tok0 + qr) * NH + h];
    bf16* og = aout + (tok0 + qr) * 2048 + h * 128;
#pragma unroll
    for (int dt = 0; dt < 8; dt++) {
      int d = dt * 16 + llo;
      float v = (ov[dt][r] - mu[r]) * rstd[r] * lng[d] + lnb[d];
      og[d] = tobf(v * gg);
    }
  }
}

// ---------------- launch ----------------
extern "C" void kernel_launch(void* const* d_in, const int* in_sizes, int n_in,
                              void* d_out, int out_size, void* d_ws, size_t ws_size,
                              hipStream_t stream) {
  (void)in_sizes; (void)n_in; (void)out_size; (void)ws_size;
  const float* X   = (const float*)d_in[0];
  const int*   pos = (const int*)d_in[1];
  const float* Wq  = (const float*)d_in[2];
  const float* Wk  = (const float*)d_in[3];
  const float* Wv  = (const float*)d_in[4];
  const float* Wo  = (const float*)d_in[5];
  const float* Wg1 = (const float*)d_in[6];
  const float* bg1 = (const float*)d_in[7];
  const float* Wg2 = (const float*)d_in[8];
  const float* bg2 = (const float*)d_in[9];
  const float* lng = (const float*)d_in[10];
  const float* lnb = (const float*)d_in[11];

  char* ws = (char*)d_ws;
  size_t off = 0;
  auto alloc = [&](size_t bytes) {
    void* p = ws + off;
    off += (bytes + 255) & ~(size_t)255;
    return p;
  };
  bf16*  WT   = (bf16*)alloc(3072ull * 2048 * 2);   // [Wq^T; Wk^T; Wv^T]  (N x K)
  bf16*  WoT  = (bf16*)alloc(2048ull * 2048 * 2);
  bf16*  Xbf  = (bf16*)alloc(4096ull * 2048 * 2);
  bf16*  qkv  = (bf16*)alloc(4096ull * 3072 * 2);
  bf16*  attn = (bf16*)alloc(4096ull * 2048 * 2);
  float* cosT = (float*)alloc(2048ull * 64 * 4);
  float* sinT = (float*)alloc(2048ull * 64 * 4);
  float* g1   = (float*)alloc(4096ull * 16 * 4);
  float* g2   = (float*)alloc(4096ull * 16 * 4);

  dim3 tb(32, 8);
  transpose_cast_k<<<dim3(64, 64), tb, 0, stream>>>(Wq, WT, 2048, 2048);
  transpose_cast_k<<<dim3(64, 16), tb, 0, stream>>>(Wk, WT + 2048ull * 2048, 2048, 512);
  transpose_cast_k<<<dim3(64, 16), tb, 0, stream>>>(Wv, WT + 2560ull * 2048, 2048, 512);
  transpose_cast_k<<<dim3(64, 64), tb, 0, stream>>>(Wo, WoT, 2048, 2048);
  cast_x_k<<<8192, 256, 0, stream>>>(X, Xbf);
  rope_table_k<<<2048, 64, 0, stream>>>(pos, cosT, sinT);
  gates_k<<<4096, 256, 0, stream>>>(X, Wg1, bg1, Wg2, bg2, g1, g2);

  // qkv = Xbf @ [Wq|Wk|Wv]  (4096 x 3072)
  gemm_bt_k<true><<<dim3(24, 32), 256, 0, stream>>>(Xbf, WT, qkv, 4096, 3072, 2048);
  rope_apply_k<<<20480, 256, 0, stream>>>(qkv, cosT, sinT);
  attn_k<<<dim3(32, 32), 256, 0, stream>>>(qkv, g1, g2, lng, lnb, attn);
  // out = attn @ Wo  (4096 x 2048), fp32
  gemm_bt_k<false><<<dim3(16, 32), 256, 0, stream>>>(attn, WoT, d_out, 4096, 2048, 2048);
}

// Round 2
// 584.420 us; speedup vs baseline: 1.2442x; 1.2442x over previous
//
#include <hip/hip_runtime.h>
#include <hip/hip_bf16.h>
#include <stdint.h>
#include <string.h>

using bf16 = __hip_bfloat16;
typedef __attribute__((ext_vector_type(8))) short bf16x8;   // 8 bf16 (4 VGPRs) MFMA A/B frag
typedef __attribute__((ext_vector_type(4))) float f32x4;    // MFMA C/D frag

#define DEV static __device__ __forceinline__

DEV bf16 tobf(float f) { return __float2bfloat16(f); }
DEV float tof(bf16 h) { return __bfloat162float(h); }
DEV unsigned short bfraw(bf16 h) { unsigned short u; __builtin_memcpy(&u, &h, 2); return u; }

// async global->LDS, 16B per lane. LDS dest semantics: wave-uniform base + lane*16.
DEV void gload_lds16(const void* g, void* l) {
  __builtin_amdgcn_global_load_lds((__attribute__((address_space(1))) void*)g,
                                   (__attribute__((address_space(3))) void*)l,
                                   16, 0, 0);
}

// ---------------- prep kernels ----------------

// dst[n][k] = (bf16)src[k][n]; src is K x N row-major. block (32,8), grid (K/32, N/32)
__global__ void transpose_cast_k(const float* __restrict__ src, bf16* __restrict__ dst,
                                 int K, int N) {
  __shared__ float tile[32][33];
  int kb = blockIdx.x * 32, nb = blockIdx.y * 32;
  int tx = threadIdx.x, ty = threadIdx.y;
#pragma unroll
  for (int i = 0; i < 32; i += 8)
    tile[ty + i][tx] = src[(size_t)(kb + ty + i) * N + nb + tx];
  __syncthreads();
#pragma unroll
  for (int i = 0; i < 32; i += 8)
    dst[(size_t)(nb + ty + i) * K + kb + tx] = tobf(tile[tx][ty + i]);
}

__global__ void cast_x_k(const float* __restrict__ src, bf16* __restrict__ dst) {
  int i = blockIdx.x * blockDim.x + threadIdx.x;  // one float4 per thread
  float4 v = ((const float4*)src)[i];
  bf16 t[4] = {tobf(v.x), tobf(v.y), tobf(v.z), tobf(v.w)};
  uint2 p; __builtin_memcpy(&p, t, 8);
  ((uint2*)dst)[i] = p;
}

// cos/sin tables: [S][64]. grid S blocks x 64 threads.
__global__ void rope_table_k(const int* __restrict__ pos, float* __restrict__ cosT,
                             float* __restrict__ sinT) {
  int s = blockIdx.x, i = threadIdx.x;
  double inv = exp(-((double)(2 * i) / 128.0) * log(10000.0));
  float f = (float)pos[s] * (float)inv;
  cosT[s * 64 + i] = cosf(f);
  sinT[s * 64 + i] = sinf(f);
}

// g1,g2 = sigmoid(X @ Wg + bg), fp32. One block per token.
__global__ __launch_bounds__(256) void gates_k(
    const float* __restrict__ X, const float* __restrict__ Wg1, const float* __restrict__ bg1,
    const float* __restrict__ Wg2, const float* __restrict__ bg2,
    float* __restrict__ g1, float* __restrict__ g2) {
  __shared__ float xs[2048];
  int t = blockIdx.x;
  const float* xr = X + (size_t)t * 2048;
  for (int i = threadIdx.x; i < 2048; i += 256) xs[i] = xr[i];
  __syncthreads();
  int o = threadIdx.x >> 3, j = threadIdx.x & 7;  // 32 outputs x 8 threads
  int h = o & 15;
  const float* W = (o < 16) ? Wg1 : Wg2;
  float s = 0.f;
  for (int k = j; k < 2048; k += 8) s += xs[k] * W[(size_t)k * 16 + h];
  s += __shfl_down(s, 4); s += __shfl_down(s, 2); s += __shfl_down(s, 1);
  if (j == 0) {
    float b = (o < 16) ? bg1[h] : bg2[h];
    float v = 1.f / (1.f + __expf(-(s + b)));
    (o < 16 ? g1 : g2)[(size_t)t * 16 + h] = v;
  }
}

// RoPE in place on qkv: q cols [0,2048), k cols [2048,2560). One thread per (token, head, pair).
__global__ void rope_apply_k(bf16* __restrict__ qkv, const float* __restrict__ cosT,
                             const float* __restrict__ sinT) {
  int idx = blockIdx.x * 256 + threadIdx.x;  // 4096 * 1280 total
  int t = idx / 1280, r = idx % 1280;
  int head = r >> 6, i = r & 63;
  int s = t & 2047;
  size_t base = (size_t)t * 3072 + (head < 16 ? head * 128 : 2048 + (head - 16) * 128);
  float c = cosT[s * 64 + i], sn = sinT[s * 64 + i];
  float x0 = tof(qkv[base + i]), x1 = tof(qkv[base + i + 64]);
  qkv[base + i]      = tobf(x0 * c - x1 * sn);
  qkv[base + i + 64] = tobf(x1 * c + x0 * sn);
}

// ---------------- GEMM: C = A(MxK) * Bt(NxK)^T ----------------
// m97 structure: 128x128 tile, BK=32, 4 waves (2x2, 64x64 each), global_load_lds x16B.
template <bool OUT_BF16>
__global__ __launch_bounds__(256, 2) void gemm_bt_k(
    const bf16* __restrict__ A, const bf16* __restrict__ Bt, void* __restrict__ Cout,
    int M, int N, int K) {
  constexpr int BK = 32;
  __shared__ bf16 sA[2][128 * BK];
  __shared__ bf16 sB[2][128 * BK];
  const int tid = threadIdx.x, wave = tid >> 6, lane = tid & 63;
  const int lhi = lane >> 4, llo = lane & 15;
  const int wm = wave >> 1, wn = wave & 1;
  const int bm = blockIdx.y, bn = blockIdx.x;
  const bf16* Ag = A + (size_t)bm * 128 * K;
  const bf16* Bg = Bt + (size_t)bn * 128 * K;

  f32x4 acc[4][4];
#pragma unroll
  for (int m = 0; m < 4; m++)
#pragma unroll
    for (int n = 0; n < 4; n++) acc[m][n] = f32x4{0.f, 0.f, 0.f, 0.f};

  auto stage = [&](int buf, int kt) {
#pragma unroll
    for (int i = 0; i < 2; i++) {
      int c = i * 256 + tid, row = c >> 2, c8 = c & 3;
      gload_lds16(Ag + (size_t)row * K + kt * BK + c8 * 8, &sA[buf][c * 8]);
    }
#pragma unroll
    for (int i = 0; i < 2; i++) {
      int c = i * 256 + tid, row = c >> 2, c8 = c & 3;
      gload_lds16(Bg + (size_t)row * K + kt * BK + c8 * 8, &sB[buf][c * 8]);
    }
  };

  const int NT = K / BK;
  stage(0, 0);
  for (int kt = 0; kt < NT; kt++) {
    __syncthreads();  // drains this wave's global_load_lds (compiler emits vmcnt(0)) + syncs
    if (kt + 1 < NT) stage((kt + 1) & 1, kt + 1);
    const bf16* a_ = sA[kt & 1];
    const bf16* b_ = sB[kt & 1];
    bf16x8 af[4], bfr[4];
#pragma unroll
    for (int m = 0; m < 4; m++)
      af[m] = *(const bf16x8*)&a_[(wm * 64 + m * 16 + llo) * BK + lhi * 8];
#pragma unroll
    for (int n = 0; n < 4; n++)
      bfr[n] = *(const bf16x8*)&b_[(wn * 64 + n * 16 + llo) * BK + lhi * 8];
#pragma unroll
    for (int m = 0; m < 4; m++)
#pragma unroll
      for (int n = 0; n < 4; n++)
        acc[m][n] = __builtin_amdgcn_mfma_f32_16x16x32_bf16(af[m], bfr[n], acc[m][n], 0, 0, 0);
  }

  const int r0 = bm * 128 + wm * 64, c0 = bn * 128 + wn * 64;
  if (OUT_BF16) {
    bf16* C = (bf16*)Cout;
#pragma unroll
    for (int m = 0; m < 4; m++)
#pragma unroll
      for (int n = 0; n < 4; n++)
#pragma unroll
        for (int r = 0; r < 4; r++)
          C[(size_t)(r0 + m * 16 + lhi * 4 + r) * N + (c0 + n * 16 + llo)] = tobf(acc[m][n][r]);
  } else {
    float* C = (float*)Cout;
#pragma unroll
    for (int m = 0; m < 4; m++)
#pragma unroll
      for (int n = 0; n < 4; n++)
#pragma unroll
        for (int r = 0; r < 4; r++)
          C[(size_t)(r0 + m * 16 + lhi * 4 + r) * N + (c0 + n * 16 + llo)] = acc[m][n][r];
  }
}

// ---------------- fused causal GQA attention + LN + gating ----------------
// 1D grid, 1024 blocks: qt DESCENDING (long blocks first -> backfill smooths the
// triangular imbalance), bh minor. 4 waves/block; wave w owns q rows [qt*64+w*16, +16).
// T14 async-STAGE: global loads for tile t+1 issued right after the compute barrier
// (in-flight during QK/softmax/PV), LDS writes after the read-completion barrier.
// g2 value-gating applied to P (o = P*(g2 (.) V) == (P*g2row) @ V) so V staging is a
// pure copy with static-index packed b64 writes (conflict-free, no scratch).
__global__ __launch_bounds__(256, 3) void attn_k(
    const bf16* __restrict__ qkv, const float* __restrict__ g1, const float* __restrict__ g2,
    const float* __restrict__ lng, const float* __restrict__ lnb, bf16* __restrict__ aout) {
  constexpr int S = 2048, LD = 3072, NH = 16;
  const int bid = blockIdx.x;
  const int qt = 31 - (bid >> 5);   // descending: longest blocks dispatch first
  const int bh = bid & 31;
  const int b = bh >> 4, h = bh & 15, kvh = h >> 2;
  const int tid = threadIdx.x, wave = tid >> 6, lane = tid & 63;
  const int lhi = lane >> 4, llo = lane & 15;
  const size_t tok0 = (size_t)b * S;

  __shared__ bf16 sK[64 * 128];   // [kv][d], XOR-swizzled ((row&7)<<3 on element idx)
  __shared__ bf16 sV[128 * 64];   // [d][kv] transposed, XOR-swizzled ((d&7)<<3)
  __shared__ bf16 sP[4][16][72];  // per-wave P tile, padded

  const int qrow0 = qt * 64 + wave * 16;

  // Q fragments held in registers for the whole block row
  bf16x8 qf[4];
  {
    const bf16* qg = qkv + (tok0 + qrow0 + llo) * LD + h * 128;
#pragma unroll
    for (int dc = 0; dc < 4; dc++) qf[dc] = *(const bf16x8*)(qg + dc * 32 + lhi * 8);
  }

  f32x4 oacc[8];
#pragma unroll
  for (int i = 0; i < 8; i++) oacc[i] = f32x4{0.f, 0.f, 0.f, 0.f};
  float mrow[4] = {-1e30f, -1e30f, -1e30f, -1e30f};
  float lrow[4] = {0.f, 0.f, 0.f, 0.f};
  const float scale = 0.08838834764831845f;  // 1/sqrt(128)

  // staging register buffers (consumed by write_lds at next loop top)
  uint4 kreg[4];
  bf16x8 vreg[4];
  const int vdg = tid >> 4;   // d-group: 8 d elems
  const int vkg = tid & 15;   // kv-group: 4 kv rows

  auto issue_loads = [&](int kt) {
    // K tile [64][128]: 4 coalesced 16B loads/thread
#pragma unroll
    for (int i = 0; i < 4; i++) {
      int c = i * 256 + tid, row = c >> 4, c8 = c & 15;
      kreg[i] = *(const uint4*)(qkv + (tok0 + kt * 64 + row) * LD + 2048 + kvh * 128 + c8 * 8);
    }
    // V tile: thread loads 4 kv rows x 8 d elems (strided across lanes; L2-hot)
#pragma unroll
    for (int r = 0; r < 4; r++)
      vreg[r] = *(const bf16x8*)(qkv + (tok0 + kt * 64 + vkg * 4 + r) * LD + 2560 +
                                 kvh * 128 + vdg * 8);
  };

  auto write_lds = [&]() {
#pragma unroll
    for (int i = 0; i < 4; i++) {
      int c = i * 256 + tid, row = c >> 4, c8 = c & 15;
      int eidx = (row * 128 + c8 * 8) ^ ((row & 7) << 3);
      *(uint4*)&sK[eidx] = kreg[i];
    }
    // V^T writes: for each d elem e (static), pack 4 kv bf16 -> b64, swizzled store.
    // Banks: lanes of a wave cover 4 contiguous 1KB d-regions uniformly -> conflict-free.
#pragma unroll
    for (int e = 0; e < 8; e++) {
      int d = vdg * 8 + e;          // d & 7 == e
      uint32_t lo = (uint32_t)(unsigned short)vreg[0][e] |
                    ((uint32_t)(unsigned short)vreg[1][e] << 16);
      uint32_t hi = (uint32_t)(unsigned short)vreg[2][e] |
                    ((uint32_t)(unsigned short)vreg[3][e] << 16);
      int eidx = (d * 64 + vkg * 4) ^ (e << 3);
      uint2 pk; pk.x = lo; pk.y = hi;
      *(uint2*)&sV[eidx] = pk;
    }
  };

  issue_loads(0);
  for (int kt = 0; kt <= qt; kt++) {
    __syncthreads();  // previous tile's LDS reads complete before overwrite (no-op at kt=0)
    write_lds();      // compiler inserts vmcnt wait on kreg/vreg here
    __syncthreads();  // LDS writes visible
    if (kt < qt) issue_loads(kt + 1);  // in flight during compute below (T14)

    // g2 for this tile's kv tokens (one per lane), used for P-gating in softmax
    float gv = g2[(tok0 + kt * 64 + lane) * NH + h];

    const bool diag = (kt == qt);
    // ---- QK^T: 4 col-tiles x 4 d-chunks ----
    f32x4 sc[4];
#pragma unroll
    for (int ct = 0; ct < 4; ct++) {
      f32x4 acc = f32x4{0.f, 0.f, 0.f, 0.f};
#pragma unroll
      for (int dc = 0; dc < 4; dc++) {
        int row = ct * 16 + llo;
        bf16x8 kf = *(const bf16x8*)&sK[(row * 128 + dc * 32 + lhi * 8) ^ ((row & 7) << 3)];
        acc = __builtin_amdgcn_mfma_f32_16x16x32_bf16(qf[dc], kf, acc, 0, 0, 0);
      }
      sc[ct] = acc;
    }
    // ---- scale + causal mask + online softmax ----
    float pm[4] = {-1e30f, -1e30f, -1e30f, -1e30f};
#pragma unroll
    for (int ct = 0; ct < 4; ct++) {
      int kv = kt * 64 + ct * 16 + llo;
#pragma unroll
      for (int r = 0; r < 4; r++) {
        float s = sc[ct][r] * scale;
        if (diag && kv > qrow0 + lhi * 4 + r) s = -1e30f;
        sc[ct][r] = s;
        pm[r] = fmaxf(pm[r], s);
      }
    }
#pragma unroll
    for (int r = 0; r < 4; r++) {
      float v = pm[r];
      v = fmaxf(v, __shfl_xor(v, 1));
      v = fmaxf(v, __shfl_xor(v, 2));
      v = fmaxf(v, __shfl_xor(v, 4));
      v = fmaxf(v, __shfl_xor(v, 8));
      float mnew = fmaxf(mrow[r], v);
      float al = __expf(mrow[r] - mnew);
      mrow[r] = mnew;
      lrow[r] *= al;
#pragma unroll
      for (int i = 0; i < 8; i++) oacc[i][r] *= al;
    }
    float g2v[4];
#pragma unroll
    for (int ct = 0; ct < 4; ct++) g2v[ct] = __shfl(gv, ct * 16 + llo);
    float rs[4] = {0.f, 0.f, 0.f, 0.f};
#pragma unroll
    for (int ct = 0; ct < 4; ct++) {
#pragma unroll
      for (int r = 0; r < 4; r++) {
        float p = __expf(sc[ct][r] - mrow[r]);
        rs[r] += p;  // softmax denom uses UNGATED p
        sP[wave][lhi * 4 + r][ct * 16 + llo] = tobf(p * g2v[ct]);
      }
    }
#pragma unroll
    for (int r = 0; r < 4; r++) {
      float v = rs[r];
      v += __shfl_xor(v, 1); v += __shfl_xor(v, 2); v += __shfl_xor(v, 4); v += __shfl_xor(v, 8);
      lrow[r] += v;
    }
    // ---- PV: O += (P*g2) * V ----
#pragma unroll
    for (int kc = 0; kc < 2; kc++) {
      bf16x8 pf = *(const bf16x8*)&sP[wave][llo][kc * 32 + lhi * 8];
#pragma unroll
      for (int dt = 0; dt < 8; dt++) {
        int d = dt * 16 + llo;
        bf16x8 vf = *(const bf16x8*)&sV[(d * 64 + kc * 32 + lhi * 8) ^ ((d & 7) << 3)];
        oacc[dt] = __builtin_amdgcn_mfma_f32_16x16x32_bf16(pf, vf, oacc[dt], 0, 0, 0);
      }
    }
  }

  // ---- epilogue: 1/l, LayerNorm over head_dim, *g1, store bf16 ----
  float inv_l[4], mu[4], rstd[4];
  float ov[8][4];
  {
    float sum[4] = {0, 0, 0, 0}, sq[4] = {0, 0, 0, 0};
#pragma unroll
    for (int r = 0; r < 4; r++) inv_l[r] = 1.f / lrow[r];
#pragma unroll
    for (int dt = 0; dt < 8; dt++)
#pragma unroll
      for (int r = 0; r < 4; r++) {
        float v = oacc[dt][r] * inv_l[r];
        ov[dt][r] = v;
        sum[r] += v;
        sq[r] += v * v;
      }
#pragma unroll
    for (int r = 0; r < 4; r++) {
      float s1 = sum[r], s2 = sq[r];
      s1 += __shfl_xor(s1, 1); s1 += __shfl_xor(s1, 2); s1 += __shfl_xor(s1, 4); s1 += __shfl_xor(s1, 8);
      s2 += __shfl_xor(s2, 1); s2 += __shfl_xor(s2, 2); s2 += __shfl_xor(s2, 4); s2 += __shfl_xor(s2, 8);
      float m_ = s1 * (1.f / 128.f);
      float var = s2 * (1.f / 128.f) - m_ * m_;
      mu[r] = m_;
      rstd[r] = rsqrtf(var + 1e-5f);
    }
  }
#pragma unroll
  for (int r = 0; r < 4; r++) {
    int qr = qrow0 + lhi * 4 + r;
    float gg = g1[(tok0 + qr) * NH + h];
    bf16* og = aout + (tok0 + qr) * 2048 + h * 128;
#pragma unroll
    for (int dt = 0; dt < 8; dt++) {
      int d = dt * 16 + llo;
      float v = (ov[dt][r] - mu[r]) * rstd[r] * lng[d] + lnb[d];
      og[d] = tobf(v * gg);
    }
  }
}

// ---------------- launch ----------------
extern "C" void kernel_launch(void* const* d_in, const int* in_sizes, int n_in,
                              void* d_out, int out_size, void* d_ws, size_t ws_size,
                              hipStream_t stream) {
  (void)in_sizes; (void)n_in; (void)out_size; (void)ws_size;
  const float* X   = (const float*)d_in[0];
  const int*   pos = (const int*)d_in[1];
  const float* Wq  = (const float*)d_in[2];
  const float* Wk  = (const float*)d_in[3];
  const float* Wv  = (const float*)d_in[4];
  const float* Wo  = (const float*)d_in[5];
  const float* Wg1 = (const float*)d_in[6];
  const float* bg1 = (const float*)d_in[7];
  const float* Wg2 = (const float*)d_in[8];
  const float* bg2 = (const float*)d_in[9];
  const float* lng = (const float*)d_in[10];
  const float* lnb = (const float*)d_in[11];

  char* ws = (char*)d_ws;
  size_t off = 0;
  auto alloc = [&](size_t bytes) {
    void* p = ws + off;
    off += (bytes + 255) & ~(size_t)255;
    return p;
  };
  bf16*  WT   = (bf16*)alloc(3072ull * 2048 * 2);   // [Wq^T; Wk^T; Wv^T]  (N x K)
  bf16*  WoT  = (bf16*)alloc(2048ull * 2048 * 2);
  bf16*  Xbf  = (bf16*)alloc(4096ull * 2048 * 2);
  bf16*  qkv  = (bf16*)alloc(4096ull * 3072 * 2);
  bf16*  attn = (bf16*)alloc(4096ull * 2048 * 2);
  float* cosT = (float*)alloc(2048ull * 64 * 4);
  float* sinT = (float*)alloc(2048ull * 64 * 4);
  float* g1   = (float*)alloc(4096ull * 16 * 4);
  float* g2   = (float*)alloc(4096ull * 16 * 4);

  dim3 tb(32, 8);
  transpose_cast_k<<<dim3(64, 64), tb, 0, stream>>>(Wq, WT, 2048, 2048);
  transpose_cast_k<<<dim3(64, 16), tb, 0, stream>>>(Wk, WT + 2048ull * 2048, 2048, 512);
  transpose_cast_k<<<dim3(64, 16), tb, 0, stream>>>(Wv, WT + 2560ull * 2048, 2048, 512);
  transpose_cast_k<<<dim3(64, 64), tb, 0, stream>>>(Wo, WoT, 2048, 2048);
  cast_x_k<<<8192, 256, 0, stream>>>(X, Xbf);
  rope_table_k<<<2048, 64, 0, stream>>>(pos, cosT, sinT);
  gates_k<<<4096, 256, 0, stream>>>(X, Wg1, bg1, Wg2, bg2, g1, g2);

  // qkv = Xbf @ [Wq|Wk|Wv]  (4096 x 3072)
  gemm_bt_k<true><<<dim3(24, 32), 256, 0, stream>>>(Xbf, WT, qkv, 4096, 3072, 2048);
  rope_apply_k<<<20480, 256, 0, stream>>>(qkv, cosT, sinT);
  attn_k<<<1024, 256, 0, stream>>>(qkv, g1, g2, lng, lnb, attn);
  // out = attn @ Wo  (4096 x 2048), fp32
  gemm_bt_k<false><<<dim3(16, 32), 256, 0, stream>>>(attn, WoT, d_out, 4096, 2048, 2048);
}

// Round 4
// 382.310 us; speedup vs baseline: 1.9020x; 1.5287x over previous
//
#include <hip/hip_runtime.h>
#include <hip/hip_bf16.h>
#include <stdint.h>
#include <string.h>

using bf16 = __hip_bfloat16;
typedef __attribute__((ext_vector_type(8))) short bf16x8;   // 8 bf16 (4 VGPRs) MFMA A/B frag
typedef __attribute__((ext_vector_type(4))) float f32x4;    // MFMA C/D frag

#define DEV static __device__ __forceinline__

DEV bf16 tobf(float f) { return __float2bfloat16(f); }
DEV float tof(bf16 h) { return __bfloat162float(h); }

// async global->LDS, 16B per lane. LDS dest semantics: wave-uniform base + lane*16.
DEV void gload_lds16(const void* g, void* l) {
  __builtin_amdgcn_global_load_lds((__attribute__((address_space(1))) void*)g,
                                   (__attribute__((address_space(3))) void*)l,
                                   16, 0, 0);
}

// ---------------- prep kernels ----------------

// dst[n][k] = (bf16)src[k][n]; src is K x N row-major. block (32,8), grid (K/32, N/32)
__global__ void transpose_cast_k(const float* __restrict__ src, bf16* __restrict__ dst,
                                 int K, int N) {
  __shared__ float tile[32][33];
  int kb = blockIdx.x * 32, nb = blockIdx.y * 32;
  int tx = threadIdx.x, ty = threadIdx.y;
#pragma unroll
  for (int i = 0; i < 32; i += 8)
    tile[ty + i][tx] = src[(size_t)(kb + ty + i) * N + nb + tx];
  __syncthreads();
#pragma unroll
  for (int i = 0; i < 32; i += 8)
    dst[(size_t)(nb + ty + i) * K + kb + tx] = tobf(tile[tx][ty + i]);
}

// Wg (2048x16) -> WT rows: dst[r][k] = Wg[k][r]. grid 32 blocks: g=bx>>4, r=bx&15.
__global__ void gw_transpose_k(const float* __restrict__ Wg1, const float* __restrict__ Wg2,
                               bf16* __restrict__ dstbase) {
  int g = blockIdx.x >> 4, r = blockIdx.x & 15;
  const float* src = g ? Wg2 : Wg1;
  bf16* dst = dstbase + (size_t)(3072 + g * 16 + r) * 2048;
  for (int k = threadIdx.x; k < 2048; k += 256) dst[k] = tobf(src[(size_t)k * 16 + r]);
}

__global__ void cast_x_k(const float* __restrict__ src, bf16* __restrict__ dst) {
  int i = blockIdx.x * blockDim.x + threadIdx.x;  // one float4 per thread
  float4 v = ((const float4*)src)[i];
  bf16 t[4] = {tobf(v.x), tobf(v.y), tobf(v.z), tobf(v.w)};
  uint2 p; __builtin_memcpy(&p, t, 8);
  ((uint2*)dst)[i] = p;
}

// cos/sin tables: [S][64]. grid S blocks x 64 threads.
__global__ void rope_table_k(const int* __restrict__ pos, float* __restrict__ cosT,
                             float* __restrict__ sinT) {
  int s = blockIdx.x, i = threadIdx.x;
  double inv = exp(-((double)(2 * i) / 128.0) * log(10000.0));
  float f = (float)pos[s] * (float)inv;
  cosT[s * 64 + i] = cosf(f);
  sinT[s * 64 + i] = sinf(f);
}

// RoPE in place on qkv, vectorized 16B: thread = (token t, head 0..19, chunk c of 8 dims).
__global__ __launch_bounds__(256) void rope_apply_k(
    bf16* __restrict__ qkv, const float* __restrict__ cosT, const float* __restrict__ sinT) {
  int idx = blockIdx.x * 256 + threadIdx.x;  // 4096*20*8 = 655360
  int c = idx & 7, hh = idx >> 3;
  int head = hh % 20, t = hh / 20;
  int s = t & 2047;
  size_t base = (size_t)t * 3072 + (head < 16 ? head * 128 : 2048 + (head - 16) * 128);
  int d0 = c * 8;
  bf16x8 lo = *(const bf16x8*)(qkv + base + d0);
  bf16x8 hi = *(const bf16x8*)(qkv + base + d0 + 64);
  float4 c0 = *(const float4*)(cosT + s * 64 + d0);
  float4 c1 = *(const float4*)(cosT + s * 64 + d0 + 4);
  float4 s0 = *(const float4*)(sinT + s * 64 + d0);
  float4 s1 = *(const float4*)(sinT + s * 64 + d0 + 4);
  float cs[8] = {c0.x, c0.y, c0.z, c0.w, c1.x, c1.y, c1.z, c1.w};
  float sn[8] = {s0.x, s0.y, s0.z, s0.w, s1.x, s1.y, s1.z, s1.w};
  bf16x8 olo, ohi;
#pragma unroll
  for (int j = 0; j < 8; j++) {
    float a = tof(((const bf16*)&lo)[j]), b = tof(((const bf16*)&hi)[j]);
    ((bf16*)&olo)[j] = tobf(a * cs[j] - b * sn[j]);
    ((bf16*)&ohi)[j] = tobf(b * cs[j] + a * sn[j]);
  }
  *(bf16x8*)(qkv + base + d0) = olo;
  *(bf16x8*)(qkv + base + d0 + 64) = ohi;
}

// ---------------- QKV+gates GEMM: [qkv | g1 | g2] = Xbf @ WT^T ----------------
// WT is 3200 x 2048 (rows: Wq^T 0..2047, Wk^T ..2559, Wv^T ..3071, Wg1^T ..3087,
// Wg2^T ..3103, garbage ..3199). Epilogue: cols<3072 -> qkv bf16 (LD 3072);
// cols 3072..3103 -> sigmoid(acc+bias) fp32 into g1/g2; cols>=3104 discarded.
__global__ __launch_bounds__(256, 2) void gemm_qkv_k(
    const bf16* __restrict__ A, const bf16* __restrict__ Bt, bf16* __restrict__ qkv,
    float* __restrict__ g1, float* __restrict__ g2,
    const float* __restrict__ bg1, const float* __restrict__ bg2) {
  constexpr int BK = 32, K = 2048;
  __shared__ bf16 sA[2][128 * BK];
  __shared__ bf16 sB[2][128 * BK];
  const int tid = threadIdx.x, wave = tid >> 6, lane = tid & 63;
  const int lhi = lane >> 4, llo = lane & 15;
  const int wm = wave >> 1, wn = wave & 1;
  const int bm = blockIdx.y, bn = blockIdx.x;
  const bf16* Ag = A + (size_t)bm * 128 * K;
  const bf16* Bg = Bt + (size_t)bn * 128 * K;

  f32x4 acc[4][4];
#pragma unroll
  for (int m = 0; m < 4; m++)
#pragma unroll
    for (int n = 0; n < 4; n++) acc[m][n] = f32x4{0.f, 0.f, 0.f, 0.f};

  auto stage = [&](int buf, int kt) {
#pragma unroll
    for (int i = 0; i < 2; i++) {
      int c = i * 256 + tid, row = c >> 2, c8 = c & 3;
      gload_lds16(Ag + (size_t)row * K + kt * BK + c8 * 8, &sA[buf][c * 8]);
    }
#pragma unroll
    for (int i = 0; i < 2; i++) {
      int c = i * 256 + tid, row = c >> 2, c8 = c & 3;
      gload_lds16(Bg + (size_t)row * K + kt * BK + c8 * 8, &sB[buf][c * 8]);
    }
  };

  const int NT = K / BK;
  stage(0, 0);
  for (int kt = 0; kt < NT; kt++) {
    __syncthreads();
    if (kt + 1 < NT) stage((kt + 1) & 1, kt + 1);
    const bf16* a_ = sA[kt & 1];
    const bf16* b_ = sB[kt & 1];
    bf16x8 af[4], bfr[4];
#pragma unroll
    for (int m = 0; m < 4; m++)
      af[m] = *(const bf16x8*)&a_[(wm * 64 + m * 16 + llo) * BK + lhi * 8];
#pragma unroll
    for (int n = 0; n < 4; n++)
      bfr[n] = *(const bf16x8*)&b_[(wn * 64 + n * 16 + llo) * BK + lhi * 8];
#pragma unroll
    for (int m = 0; m < 4; m++)
#pragma unroll
      for (int n = 0; n < 4; n++)
        acc[m][n] = __builtin_amdgcn_mfma_f32_16x16x32_bf16(af[m], bfr[n], acc[m][n], 0, 0, 0);
  }

  const int r0 = bm * 128 + wm * 64, c0 = bn * 128 + wn * 64;
#pragma unroll
  for (int m = 0; m < 4; m++)
#pragma unroll
    for (int n = 0; n < 4; n++) {
      int col = c0 + n * 16 + llo;
#pragma unroll
      for (int r = 0; r < 4; r++) {
        int row = r0 + m * 16 + lhi * 4 + r;
        if (col < 3072) {
          qkv[(size_t)row * 3072 + col] = tobf(acc[m][n][r]);
        } else if (col < 3104) {
          int idx = col - 3072, hh = idx & 15;
          float b = (idx < 16) ? bg1[hh] : bg2[hh];
          float v = 1.f / (1.f + __expf(-(acc[m][n][r] + b)));
          ((idx < 16) ? g1 : g2)[(size_t)row * 16 + hh] = v;
        }
      }
    }
}

// ---------------- generic GEMM: C = A(MxK) * Bt(NxK)^T, fp32 out ----------------
__global__ __launch_bounds__(256, 2) void gemm_out_k(
    const bf16* __restrict__ A, const bf16* __restrict__ Bt, float* __restrict__ C,
    int M, int N, int K) {
  constexpr int BK = 32;
  __shared__ bf16 sA[2][128 * BK];
  __shared__ bf16 sB[2][128 * BK];
  const int tid = threadIdx.x, wave = tid >> 6, lane = tid & 63;
  const int lhi = lane >> 4, llo = lane & 15;
  const int wm = wave >> 1, wn = wave & 1;
  const int bm = blockIdx.y, bn = blockIdx.x;
  const bf16* Ag = A + (size_t)bm * 128 * K;
  const bf16* Bg = Bt + (size_t)bn * 128 * K;

  f32x4 acc[4][4];
#pragma unroll
  for (int m = 0; m < 4; m++)
#pragma unroll
    for (int n = 0; n < 4; n++) acc[m][n] = f32x4{0.f, 0.f, 0.f, 0.f};

  auto stage = [&](int buf, int kt) {
#pragma unroll
    for (int i = 0; i < 2; i++) {
      int c = i * 256 + tid, row = c >> 2, c8 = c & 3;
      gload_lds16(Ag + (size_t)row * K + kt * BK + c8 * 8, &sA[buf][c * 8]);
    }
#pragma unroll
    for (int i = 0; i < 2; i++) {
      int c = i * 256 + tid, row = c >> 2, c8 = c & 3;
      gload_lds16(Bg + (size_t)row * K + kt * BK + c8 * 8, &sB[buf][c * 8]);
    }
  };

  const int NT = K / BK;
  stage(0, 0);
  for (int kt = 0; kt < NT; kt++) {
    __syncthreads();
    if (kt + 1 < NT) stage((kt + 1) & 1, kt + 1);
    const bf16* a_ = sA[kt & 1];
    const bf16* b_ = sB[kt & 1];
    bf16x8 af[4], bfr[4];
#pragma unroll
    for (int m = 0; m < 4; m++)
      af[m] = *(const bf16x8*)&a_[(wm * 64 + m * 16 + llo) * BK + lhi * 8];
#pragma unroll
    for (int n = 0; n < 4; n++)
      bfr[n] = *(const bf16x8*)&b_[(wn * 64 + n * 16 + llo) * BK + lhi * 8];
#pragma unroll
    for (int m = 0; m < 4; m++)
#pragma unroll
      for (int n = 0; n < 4; n++)
        acc[m][n] = __builtin_amdgcn_mfma_f32_16x16x32_bf16(af[m], bfr[n], acc[m][n], 0, 0, 0);
  }

  const int r0 = bm * 128 + wm * 64, c0 = bn * 128 + wn * 64;
#pragma unroll
  for (int m = 0; m < 4; m++)
#pragma unroll
    for (int n = 0; n < 4; n++)
#pragma unroll
      for (int r = 0; r < 4; r++)
        C[(size_t)(r0 + m * 16 + lhi * 4 + r) * N + (c0 + n * 16 + llo)] = acc[m][n][r];
}

// ---------------- fused causal GQA attention + LN + gating ----------------
// 1D grid, 1024 blocks, qt DESCENDING. 4 waves/block; wave w owns q rows [qt*64+w*16,+16).
// T14 async-STAGE: K/V/g2 loads for tile t+1 issued right after compute barrier; the g2
// value is prefetched WITH kreg/vreg so its vmcnt wait lands at write_lds (data already
// arrived), not mid-softmax (which would drain the whole prefetch queue).
// Epilogue: stage gated/normalized tile in sK, then cooperative uint4 stores (fixes the
// 16x write amplification of scalar bf16 stores).
__global__ __launch_bounds__(256, 3) void attn_k(
    const bf16* __restrict__ qkv, const float* __restrict__ g1, const float* __restrict__ g2,
    const float* __restrict__ lng, const float* __restrict__ lnb, bf16* __restrict__ aout) {
  constexpr int S = 2048, LD = 3072, NH = 16;
  const int bid = blockIdx.x;
  const int qt = 31 - (bid >> 5);   // descending: longest blocks dispatch first
  const int bh = bid & 31;
  const int b = bh >> 4, h = bh & 15, kvh = h >> 2;
  const int tid = threadIdx.x, wave = tid >> 6, lane = tid & 63;
  const int lhi = lane >> 4, llo = lane & 15;
  const size_t tok0 = (size_t)b * S;

  __shared__ bf16 sK[64 * 128];   // [kv][d], XOR-swizzled ((row&7)<<3 on element idx)
  __shared__ bf16 sV[128 * 64];   // [d][kv] transposed, XOR-swizzled ((d&7)<<3)
  __shared__ bf16 sP[4][16][72];  // per-wave P tile, padded

  const int qrow0 = qt * 64 + wave * 16;

  bf16x8 qf[4];
  {
    const bf16* qg = qkv + (tok0 + qrow0 + llo) * LD + h * 128;
#pragma unroll
    for (int dc = 0; dc < 4; dc++) qf[dc] = *(const bf16x8*)(qg + dc * 32 + lhi * 8);
  }

  f32x4 oacc[8];
#pragma unroll
  for (int i = 0; i < 8; i++) oacc[i] = f32x4{0.f, 0.f, 0.f, 0.f};
  float mrow[4] = {-1e30f, -1e30f, -1e30f, -1e30f};
  float lrow[4] = {0.f, 0.f, 0.f, 0.f};
  const float scale = 0.08838834764831845f;  // 1/sqrt(128)

  // staging register buffers (consumed by write_lds at next loop top)
  uint4 kreg[4];
  bf16x8 vreg[4];
  float gvreg;
  const int vdg = tid >> 4;   // d-group: 8 d elems
  const int vkg = tid & 15;   // kv-group: 4 kv rows

  auto issue_loads = [&](int kt) {
#pragma unroll
    for (int i = 0; i < 4; i++) {
      int c = i * 256 + tid, row = c >> 4, c8 = c & 15;
      kreg[i] = *(const uint4*)(qkv + (tok0 + kt * 64 + row) * LD + 2048 + kvh * 128 + c8 * 8);
    }
#pragma unroll
    for (int r = 0; r < 4; r++)
      vreg[r] = *(const bf16x8*)(qkv + (tok0 + kt * 64 + vkg * 4 + r) * LD + 2560 +
                                 kvh * 128 + vdg * 8);
    gvreg = g2[(tok0 + kt * 64 + lane) * NH + h];  // prefetched with K/V (T14)
  };

  auto write_lds = [&]() {
#pragma unroll
    for (int i = 0; i < 4; i++) {
      int c = i * 256 + tid, row = c >> 4, c8 = c & 15;
      int eidx = (row * 128 + c8 * 8) ^ ((row & 7) << 3);
      *(uint4*)&sK[eidx] = kreg[i];
    }
#pragma unroll
    for (int e = 0; e < 8; e++) {
      int d = vdg * 8 + e;          // d & 7 == e
      uint32_t lo = (uint32_t)(unsigned short)vreg[0][e] |
                    ((uint32_t)(unsigned short)vreg[1][e] << 16);
      uint32_t hi = (uint32_t)(unsigned short)vreg[2][e] |
                    ((uint32_t)(unsigned short)vreg[3][e] << 16);
      int eidx = (d * 64 + vkg * 4) ^ (e << 3);
      uint2 pk; pk.x = lo; pk.y = hi;
      *(uint2*)&sV[eidx] = pk;
    }
  };

  issue_loads(0);
  for (int kt = 0; kt <= qt; kt++) {
    __syncthreads();  // previous tile's LDS reads complete before overwrite
    write_lds();      // vmcnt wait for kreg/vreg/gvreg lands here (data long arrived)
    float gv = gvreg; // copy before re-issue overwrites the staging reg
    __syncthreads();  // LDS writes visible
    if (kt < qt) issue_loads(kt + 1);  // in flight during compute below (T14)

    const bool diag = (kt == qt);
    // ---- QK^T ----
    f32x4 sc[4];
#pragma unroll
    for (int ct = 0; ct < 4; ct++) {
      f32x4 acc = f32x4{0.f, 0.f, 0.f, 0.f};
#pragma unroll
      for (int dc = 0; dc < 4; dc++) {
        int row = ct * 16 + llo;
        bf16x8 kf = *(const bf16x8*)&sK[(row * 128 + dc * 32 + lhi * 8) ^ ((row & 7) << 3)];
        acc = __builtin_amdgcn_mfma_f32_16x16x32_bf16(qf[dc], kf, acc, 0, 0, 0);
      }
      sc[ct] = acc;
    }
    // ---- scale + causal mask + online softmax ----
    float pm[4] = {-1e30f, -1e30f, -1e30f, -1e30f};
#pragma unroll
    for (int ct = 0; ct < 4; ct++) {
      int kv = kt * 64 + ct * 16 + llo;
#pragma unroll
      for (int r = 0; r < 4; r++) {
        float s = sc[ct][r] * scale;
        if (diag && kv > qrow0 + lhi * 4 + r) s = -1e30f;
        sc[ct][r] = s;
        pm[r] = fmaxf(pm[r], s);
      }
    }
#pragma unroll
    for (int r = 0; r < 4; r++) {
      float v = pm[r];
      v = fmaxf(v, __shfl_xor(v, 1));
      v = fmaxf(v, __shfl_xor(v, 2));
      v = fmaxf(v, __shfl_xor(v, 4));
      v = fmaxf(v, __shfl_xor(v, 8));
      float mnew = fmaxf(mrow[r], v);
      float al = __expf(mrow[r] - mnew);
      mrow[r] = mnew;
      lrow[r] *= al;
#pragma unroll
      for (int i = 0; i < 8; i++) oacc[i][r] *= al;
    }
    float g2v[4];
#pragma unroll
    for (int ct = 0; ct < 4; ct++) g2v[ct] = __shfl(gv, ct * 16 + llo);
    float rs[4] = {0.f, 0.f, 0.f, 0.f};
#pragma unroll
    for (int ct = 0; ct < 4; ct++) {
#pragma unroll
      for (int r = 0; r < 4; r++) {
        float p = __expf(sc[ct][r] - mrow[r]);
        rs[r] += p;  // softmax denom uses UNGATED p
        sP[wave][lhi * 4 + r][ct * 16 + llo] = tobf(p * g2v[ct]);
      }
    }
#pragma unroll
    for (int r = 0; r < 4; r++) {
      float v = rs[r];
      v += __shfl_xor(v, 1); v += __shfl_xor(v, 2); v += __shfl_xor(v, 4); v += __shfl_xor(v, 8);
      lrow[r] += v;
    }
    // ---- PV: O += (P*g2) * V ----
#pragma unroll
    for (int kc = 0; kc < 2; kc++) {
      bf16x8 pf = *(const bf16x8*)&sP[wave][llo][kc * 32 + lhi * 8];
#pragma unroll
      for (int dt = 0; dt < 8; dt++) {
        int d = dt * 16 + llo;
        bf16x8 vf = *(const bf16x8*)&sV[(d * 64 + kc * 32 + lhi * 8) ^ ((d & 7) << 3)];
        oacc[dt] = __builtin_amdgcn_mfma_f32_16x16x32_bf16(pf, vf, oacc[dt], 0, 0, 0);
      }
    }
  }

  // ---- epilogue: 1/l, LayerNorm, *g1 -> stage in sK -> coalesced uint4 stores ----
  {
    float inv_l[4], mu[4], rstd[4];
    float ov[8][4];
    float sum[4] = {0, 0, 0, 0}, sq[4] = {0, 0, 0, 0};
#pragma unroll
    for (int r = 0; r < 4; r++) inv_l[r] = 1.f / lrow[r];
#pragma unroll
    for (int dt = 0; dt < 8; dt++)
#pragma unroll
      for (int r = 0; r < 4; r++) {
        float v = oacc[dt][r] * inv_l[r];
        ov[dt][r] = v;
        sum[r] += v;
        sq[r] += v * v;
      }
#pragma unroll
    for (int r = 0; r < 4; r++) {
      float s1 = sum[r], s2 = sq[r];
      s1 += __shfl_xor(s1, 1); s1 += __shfl_xor(s1, 2); s1 += __shfl_xor(s1, 4); s1 += __shfl_xor(s1, 8);
      s2 += __shfl_xor(s2, 1); s2 += __shfl_xor(s2, 2); s2 += __shfl_xor(s2, 4); s2 += __shfl_xor(s2, 8);
      float m_ = s1 * (1.f / 128.f);
      float var = s2 * (1.f / 128.f) - m_ * m_;
      mu[r] = m_;
      rstd[r] = rsqrtf(var + 1e-5f);
    }
    __syncthreads();  // done reading sK/sV in main loop
#pragma unroll
    for (int r = 0; r < 4; r++) {
      int qr = qrow0 + lhi * 4 + r;
      float gg = g1[(tok0 + qr) * NH + h];
      int lrow_ = wave * 16 + lhi * 4 + r;
#pragma unroll
      for (int dt = 0; dt < 8; dt++) {
        int d = dt * 16 + llo;
        float v = (ov[dt][r] - mu[r]) * rstd[r] * lng[d] + lnb[d];
        sK[lrow_ * 128 + d] = tobf(v * gg);
      }
    }
    __syncthreads();
#pragma unroll
    for (int i = 0; i < 4; i++) {
      int c = i * 256 + tid, lr = c >> 4, c8 = c & 15;
      *(uint4*)(aout + (tok0 + qt * 64 + lr) * 2048 + h * 128 + c8 * 8) =
          *(const uint4*)&sK[lr * 128 + c8 * 8];
    }
  }
}

// ---------------- launch ----------------
extern "C" void kernel_launch(void* const* d_in, const int* in_sizes, int n_in,
                              void* d_out, int out_size, void* d_ws, size_t ws_size,
                              hipStream_t stream) {
  (void)in_sizes; (void)n_in; (void)out_size; (void)ws_size;
  const float* X   = (const float*)d_in[0];
  const int*   pos = (const int*)d_in[1];
  const float* Wq  = (const float*)d_in[2];
  const float* Wk  = (const float*)d_in[3];
  const float* Wv  = (const float*)d_in[4];
  const float* Wo  = (const float*)d_in[5];
  const float* Wg1 = (const float*)d_in[6];
  const float* bg1 = (const float*)d_in[7];
  const float* Wg2 = (const float*)d_in[8];
  const float* bg2 = (const float*)d_in[9];
  const float* lng = (const float*)d_in[10];
  const float* lnb = (const float*)d_in[11];

  char* ws = (char*)d_ws;
  size_t off = 0;
  auto alloc = [&](size_t bytes) {
    void* p = ws + off;
    off += (bytes + 255) & ~(size_t)255;
    return p;
  };
  bf16*  WT   = (bf16*)alloc(3200ull * 2048 * 2);   // [Wq^T; Wk^T; Wv^T; Wg1^T; Wg2^T; pad]
  bf16*  WoT  = (bf16*)alloc(2048ull * 2048 * 2);
  bf16*  Xbf  = (bf16*)alloc(4096ull * 2048 * 2);
  bf16*  qkv  = (bf16*)alloc(4096ull * 3072 * 2);
  bf16*  attn = (bf16*)alloc(4096ull * 2048 * 2);
  float* cosT = (float*)alloc(2048ull * 64 * 4);
  float* sinT = (float*)alloc(2048ull * 64 * 4);
  float* g1   = (float*)alloc(4096ull * 16 * 4);
  float* g2   = (float*)alloc(4096ull * 16 * 4);

  dim3 tb(32, 8);
  transpose_cast_k<<<dim3(64, 64), tb, 0, stream>>>(Wq, WT, 2048, 2048);
  transpose_cast_k<<<dim3(64, 16), tb, 0, stream>>>(Wk, WT + 2048ull * 2048, 2048, 512);
  transpose_cast_k<<<dim3(64, 16), tb, 0, stream>>>(Wv, WT + 2560ull * 2048, 2048, 512);
  transpose_cast_k<<<dim3(64, 64), tb, 0, stream>>>(Wo, WoT, 2048, 2048);
  gw_transpose_k<<<32, 256, 0, stream>>>(Wg1, Wg2, WT);
  cast_x_k<<<8192, 256, 0, stream>>>(X, Xbf);
  rope_table_k<<<2048, 64, 0, stream>>>(pos, cosT, sinT);

  // [qkv | g1 | g2] = Xbf @ WT^T  (4096 x 3200)
  gemm_qkv_k<<<dim3(25, 32), 256, 0, stream>>>(Xbf, WT, qkv, g1, g2, bg1, bg2);
  rope_apply_k<<<2560, 256, 0, stream>>>(qkv, cosT, sinT);
  attn_k<<<1024, 256, 0, stream>>>(qkv, g1, g2, lng, lnb, attn);
  // out = attn @ Wo  (4096 x 2048), fp32
  gemm_out_k<<<dim3(16, 32), 256, 0, stream>>>(attn, WoT, (float*)d_out, 4096, 2048, 2048);
}